// Round 1
// baseline (955.308 us; speedup 1.0000x reference)
//
#include <hip/hip_runtime.h>
#include <cstdint>
#include <cstddef>

// Padded activation plane: 256x256 interior, 1-row halo top/bottom,
// interior columns start at COL0=4 so float4 stores are 16B aligned.
#define ROWS   258
#define STRIDE 264
#define PLANE  (ROWS * STRIDE)   // 68112 floats per (a,channel) plane
#define COL0   4

// ---------------------------------------------------------------------------
// Zero halo borders of both ping-pong buffers + zero the mask-format flag.
// grid: 512 blocks (256 planes x 2 buffers), 256 threads
__global__ void zero_borders_kernel(float* bufA, float* bufB, int* flag) {
    if (blockIdx.x == 0 && threadIdx.x == 0) *flag = 0;
    float* buf = (blockIdx.x < 256) ? bufA : bufB;
    float* p = buf + (size_t)(blockIdx.x & 255) * PLANE;
    int t = threadIdx.x;
    for (int c = t; c < STRIDE; c += 256) {
        p[c] = 0.0f;
        p[(size_t)(ROWS - 1) * STRIDE + c] = 0.0f;
    }
    int r = t + 1;  // rows 1..256
    if (r <= 256) {
        float* rp = p + (size_t)r * STRIDE;
        rp[0] = 0.0f; rp[1] = 0.0f; rp[2] = 0.0f; rp[3] = 0.0f;
        rp[STRIDE - 4] = 0.0f; rp[STRIDE - 3] = 0.0f;
        rp[STRIDE - 2] = 0.0f; rp[STRIDE - 1] = 0.0f;
    }
}

// ---------------------------------------------------------------------------
// Detect x_mask storage format: 0 = int32 {0,1}, 1 = bytes {0,1}, 2 = float32.
// Scans the first 32768 32-bit words (= 131072 bytes, safe in all layouts).
__global__ void detect_mask_kernel(const unsigned int* m, int* flag) {
    int i = blockIdx.x * blockDim.x + threadIdx.x;  // 8192 threads
    int f = 0;
    #pragma unroll
    for (int k = 0; k < 4; ++k) {
        unsigned int v = m[i * 4 + k];
        if (v == 0x3F800000u) f |= 2;        // 1.0f pattern -> float mask
        else if (v > 1u) f |= 1;             // packed bytes
    }
    if (f) atomicOr(flag, f);
}

// ---------------------------------------------------------------------------
// Layer 0: 1 -> 64 channels. grid: (y=256, co=64, a=4), 256 threads = x.
__global__ void conv_first_kernel(const float* __restrict__ img,
                                  const float* __restrict__ cw0,
                                  const float* __restrict__ cb0,
                                  float* __restrict__ out) {
    int y = blockIdx.x, co = blockIdx.y, a = blockIdx.z;
    int x = threadIdx.x;
    const float* w = cw0 + (size_t)(a * 64 + co) * 9;
    float acc = cb0[a * 64 + co];
    #pragma unroll
    for (int dy = 0; dy < 3; ++dy) {
        int yy = y + dy - 1;
        if (yy < 0 || yy > 255) continue;
        #pragma unroll
        for (int dx = 0; dx < 3; ++dx) {
            int xx = x + dx - 1;
            if (xx >= 0 && xx <= 255)
                acc = fmaf(w[dy * 3 + dx], img[(size_t)yy * 256 + xx], acc);
        }
    }
    acc = fmaxf(acc, 0.0f);
    out[(size_t)(a * 64 + co) * PLANE + (size_t)(y + 1) * STRIDE + (x + COL0)] = acc;
}

// ---------------------------------------------------------------------------
// Mid layers: 64 -> 64 + ReLU.
// lane = output channel (64), wave = 4x8 pixel tile, 8 waves/block.
// Input pixels are wave-uniform -> scalar loads; weights per-lane vector loads.
// grid: dim3(16,16,4) = 1024 blocks, 512 threads.
__global__ __launch_bounds__(512, 4)
void conv_mid_kernel(const float* __restrict__ in,
                     const float* __restrict__ cw,
                     const float* __restrict__ cb,
                     float* __restrict__ out) {
    int tid  = threadIdx.x;
    int lane = tid & 63;
    int wave = __builtin_amdgcn_readfirstlane(tid >> 6);  // 0..7, uniform
    int a  = blockIdx.z;
    int X0 = blockIdx.x * 16 + (wave & 1) * 8;   // pixel col base (mult of 8)
    int Y0 = blockIdx.y * 16 + (wave >> 1) * 4;  // pixel row base (mult of 4)

    float bias = cb[a * 64 + lane];
    float acc[32];
    #pragma unroll
    for (int i = 0; i < 32; ++i) acc[i] = bias;

    const float* wbase = cw + (size_t)((a * 64 + lane) * 64) * 9;
    // padded row for pixel (Y0-1) is Y0; padded col for pixel (X0-1) is X0+COL0-1
    const float* ibase = in + (size_t)a * 64 * PLANE
                            + (size_t)Y0 * STRIDE + (X0 + COL0 - 1);

    for (int ci = 0; ci < 64; ++ci) {
        const float* ip = ibase + (size_t)ci * PLANE;  // uniform address
        float s[6][10];
        #pragma unroll
        for (int r = 0; r < 6; ++r)
            #pragma unroll
            for (int c = 0; c < 10; ++c)
                s[r][c] = ip[r * STRIDE + c];

        const float* wp = wbase + ci * 9;  // per-lane
        float w0 = wp[0], w1 = wp[1], w2 = wp[2];
        float w3 = wp[3], w4 = wp[4], w5 = wp[5];
        float w6 = wp[6], w7 = wp[7], w8 = wp[8];

        #pragma unroll
        for (int r = 0; r < 4; ++r) {
            #pragma unroll
            for (int c = 0; c < 8; ++c) {
                float v = acc[r * 8 + c];
                v = fmaf(w0, s[r    ][c    ], v);
                v = fmaf(w1, s[r    ][c + 1], v);
                v = fmaf(w2, s[r    ][c + 2], v);
                v = fmaf(w3, s[r + 1][c    ], v);
                v = fmaf(w4, s[r + 1][c + 1], v);
                v = fmaf(w5, s[r + 1][c + 2], v);
                v = fmaf(w6, s[r + 2][c    ], v);
                v = fmaf(w7, s[r + 2][c + 1], v);
                v = fmaf(w8, s[r + 2][c + 2], v);
                acc[r * 8 + c] = v;
            }
        }
    }

    float* obase = out + (size_t)(a * 64 + lane) * PLANE
                       + (size_t)(Y0 + 1) * STRIDE + (X0 + COL0);
    #pragma unroll
    for (int r = 0; r < 4; ++r) {
        float4 v0, v1;
        v0.x = fmaxf(acc[r * 8 + 0], 0.0f);
        v0.y = fmaxf(acc[r * 8 + 1], 0.0f);
        v0.z = fmaxf(acc[r * 8 + 2], 0.0f);
        v0.w = fmaxf(acc[r * 8 + 3], 0.0f);
        v1.x = fmaxf(acc[r * 8 + 4], 0.0f);
        v1.y = fmaxf(acc[r * 8 + 5], 0.0f);
        v1.z = fmaxf(acc[r * 8 + 6], 0.0f);
        v1.w = fmaxf(acc[r * 8 + 7], 0.0f);
        *(float4*)(obase + (size_t)r * STRIDE)     = v0;
        *(float4*)(obase + (size_t)r * STRIDE + 4) = v1;
    }
}

// ---------------------------------------------------------------------------
// Layer 4: 64 -> 1, no ReLU. grid: (y=256, a=4), 256 threads = x.
__global__ void conv_last_kernel(const float* __restrict__ in,
                                 const float* __restrict__ cw4,
                                 const float* __restrict__ cb4,
                                 float* __restrict__ W_a) {
    int y = blockIdx.x, a = blockIdx.y;
    int x = threadIdx.x;
    const float* w = cw4 + (size_t)a * 64 * 9;
    float acc = cb4[a];
    const float* ib = in + (size_t)a * 64 * PLANE
                         + (size_t)y * STRIDE + (x + COL0 - 1);
    for (int ci = 0; ci < 64; ++ci) {
        const float* ip = ib + (size_t)ci * PLANE;
        const float* wp = w + ci * 9;
        #pragma unroll
        for (int dy = 0; dy < 3; ++dy)
            #pragma unroll
            for (int dx = 0; dx < 3; ++dx)
                acc = fmaf(wp[dy * 3 + dx], ip[(size_t)dy * STRIDE + dx], acc);
    }
    W_a[((size_t)a * 256 + y) * 256 + x] = acc;
}

// ---------------------------------------------------------------------------
// Wy[b,x] = sum_h y[b,h] * W_a[actions[b]][h,x]. grid 32, 256 threads.
__global__ void wy_kernel(const float* __restrict__ yv,
                          const int* __restrict__ actions,
                          const float* __restrict__ W_a,
                          float* __restrict__ Wy) {
    int b = blockIdx.x, x = threadIdx.x;
    int a = actions[b];
    const float* Wp = W_a + (size_t)a * 65536;
    const float* yb = yv + b * 256;
    float acc = 0.0f;
    #pragma unroll 8
    for (int h = 0; h < 256; ++h)
        acc = fmaf(yb[h], Wp[(size_t)h * 256 + x], acc);
    Wy[b * 256 + x] = acc;
}

// ---------------------------------------------------------------------------
// logits[b,l] = mask ? -inf : x[b,l,:]·Wy[b,:]. grid dim3(32 lchunks, 32 b), 256 thr.
__global__ void logits_kernel(const float* __restrict__ xv,
                              const void* __restrict__ mask,
                              const int* __restrict__ flag,
                              const float* __restrict__ Wy,
                              float* __restrict__ out) {
    int tid = threadIdx.x, lane = tid & 63, wave = tid >> 6;
    int b = blockIdx.y;
    int fl = *flag;
    float4 wy4 = *(const float4*)(Wy + b * 256 + lane * 4);
    const float* xb = xv + (size_t)b * 4096 * 256;
    int l0 = blockIdx.x * 128 + wave * 32;
    for (int li = 0; li < 32; ++li) {
        int l = l0 + li;
        const float4 x4 = *(const float4*)(xb + (size_t)l * 256 + lane * 4);
        float p = x4.x * wy4.x + x4.y * wy4.y + x4.z * wy4.z + x4.w * wy4.w;
        #pragma unroll
        for (int off = 32; off > 0; off >>= 1)
            p += __shfl_xor(p, off, 64);
        if (lane == 0) {
            size_t mi = (size_t)b * 4096 + l;
            bool msk;
            if (fl & 2)      msk = ((const float*)mask)[mi] != 0.0f;
            else if (fl & 1) msk = ((const unsigned char*)mask)[mi] != 0;
            else             msk = ((const int*)mask)[mi] != 0;
            out[mi] = msk ? -__builtin_inff() : p;
        }
    }
}

// ---------------------------------------------------------------------------
// In-place softmax over rows of 4096. grid 32, 1024 threads.
__global__ void softmax_kernel(float* __restrict__ out) {
    int b = blockIdx.x, tid = threadIdx.x;
    int lane = tid & 63, wid = tid >> 6;  // 16 waves
    float* row = out + (size_t)b * 4096;
    float v[4];
    float m = -__builtin_inff();
    #pragma unroll
    for (int i = 0; i < 4; ++i) { v[i] = row[tid + i * 1024]; m = fmaxf(m, v[i]); }
    #pragma unroll
    for (int off = 32; off > 0; off >>= 1) m = fmaxf(m, __shfl_xor(m, off, 64));
    __shared__ float redm[16];
    __shared__ float reds[16];
    if (lane == 0) redm[wid] = m;
    __syncthreads();
    float M = redm[0];
    #pragma unroll
    for (int j = 1; j < 16; ++j) M = fmaxf(M, redm[j]);
    float s = 0.0f;
    #pragma unroll
    for (int i = 0; i < 4; ++i) { v[i] = expf(v[i] - M); s += v[i]; }
    #pragma unroll
    for (int off = 32; off > 0; off >>= 1) s += __shfl_xor(s, off, 64);
    if (lane == 0) reds[wid] = s;
    __syncthreads();
    float S = 0.0f;
    #pragma unroll
    for (int j = 0; j < 16; ++j) S += reds[j];
    float inv = 1.0f / S;
    #pragma unroll
    for (int i = 0; i < 4; ++i) row[tid + i * 1024] = v[i] * inv;
}

// ---------------------------------------------------------------------------
extern "C" void kernel_launch(void* const* d_in, const int* in_sizes, int n_in,
                              void* d_out, int out_size, void* d_ws, size_t ws_size,
                              hipStream_t stream) {
    const float* xv      = (const float*)d_in[0];   // [32,4096,256]
    const float* yv      = (const float*)d_in[1];   // [32,256]
    const void*  xmask   = d_in[2];                 // [32,4096] (format detected)
    const int*   actions = (const int*)d_in[3];     // [32]
    const float* weight  = (const float*)d_in[4];   // [256,256]
    const float* cw0 = (const float*)d_in[5];
    const float* cb0 = (const float*)d_in[6];
    const float* cw1 = (const float*)d_in[7];
    const float* cb1 = (const float*)d_in[8];
    const float* cw2 = (const float*)d_in[9];
    const float* cb2 = (const float*)d_in[10];
    const float* cw3 = (const float*)d_in[11];
    const float* cb3 = (const float*)d_in[12];
    const float* cw4 = (const float*)d_in[13];
    const float* cb4 = (const float*)d_in[14];
    float* out = (float*)d_out;

    float* bufA = (float*)d_ws;
    float* bufB = bufA + (size_t)256 * PLANE;
    float* W_a  = bufB + (size_t)256 * PLANE;     // [4,256,256]
    float* Wy   = W_a + (size_t)4 * 65536;        // [32,256]
    int*   flag = (int*)(Wy + 32 * 256);

    zero_borders_kernel<<<512, 256, 0, stream>>>(bufA, bufB, flag);
    detect_mask_kernel<<<32, 256, 0, stream>>>((const unsigned int*)xmask, flag);

    conv_first_kernel<<<dim3(256, 64, 4), 256, 0, stream>>>(weight, cw0, cb0, bufA);
    conv_mid_kernel<<<dim3(16, 16, 4), 512, 0, stream>>>(bufA, cw1, cb1, bufB);
    conv_mid_kernel<<<dim3(16, 16, 4), 512, 0, stream>>>(bufB, cw2, cb2, bufA);
    conv_mid_kernel<<<dim3(16, 16, 4), 512, 0, stream>>>(bufA, cw3, cb3, bufB);
    conv_last_kernel<<<dim3(256, 4), 256, 0, stream>>>(bufB, cw4, cb4, W_a);

    wy_kernel<<<32, 256, 0, stream>>>(yv, actions, W_a, Wy);
    logits_kernel<<<dim3(32, 32), 256, 0, stream>>>(xv, xmask, flag, Wy, out);
    softmax_kernel<<<32, 1024, 0, stream>>>(out);
}

// Round 2
// 403.097 us; speedup vs baseline: 2.3699x; 2.3699x over previous
//
#include <hip/hip_runtime.h>
#include <cstdint>
#include <cstddef>

typedef __attribute__((ext_vector_type(8))) short bf16x8;
typedef __attribute__((ext_vector_type(4))) float f32x4;
typedef __attribute__((ext_vector_type(4))) int i32x4;

__device__ inline unsigned short cvt_bf16_rne(float f) {
    unsigned u = __builtin_bit_cast(unsigned, f);
    u = (u + 0x7FFFu + ((u >> 16) & 1u)) >> 16;
    return (unsigned short)u;
}
__device__ inline float bf16_to_f32(unsigned short s) {
    return __builtin_bit_cast(float, (unsigned)s << 16);
}

// ---------------------------------------------------------------------------
__global__ void clear_flag_kernel(int* flag) {
    if (threadIdx.x == 0) *flag = 0;
}

// Detect x_mask storage format: 0 = int32 {0,1}, 1 = bytes {0,1}, 2 = float32.
__global__ void detect_mask_kernel(const unsigned int* m, int* flag) {
    int i = blockIdx.x * blockDim.x + threadIdx.x;  // 8192 threads
    int f = 0;
    #pragma unroll
    for (int k = 0; k < 4; ++k) {
        unsigned int v = m[i * 4 + k];
        if (v == 0x3F800000u) f |= 2;
        else if (v > 1u) f |= 1;
    }
    if (f) atomicOr(flag, f);
}

// ---------------------------------------------------------------------------
// Pack mid-layer weights into MFMA A-fragment lane order (bf16).
// Out: apack[a][tap][ks][mf][lane][8 bf16]; value = W[a][co=mf*16+(lane&15)]
//      [ci=ks*32+(lane>>4)*8+j][tap].  One launch per layer.
// grid dim3(9,4), 512 threads.
__global__ void apack_kernel(const float* __restrict__ cw, char* __restrict__ apack) {
    int t = threadIdx.x;
    int tap = blockIdx.x, a = blockIdx.y;
    int ks = t >> 8, mf = (t >> 6) & 3, lane = t & 63;
    int n = lane & 15, q = lane >> 4;
    int co = mf * 16 + n;
    int ci0 = ks * 32 + q * 8;
    unsigned d[4];
    #pragma unroll
    for (int jj = 0; jj < 4; ++jj) {
        unsigned short h0 = cvt_bf16_rne(cw[((size_t)(a * 64 + co) * 64 + ci0 + 2 * jj + 0) * 9 + tap]);
        unsigned short h1 = cvt_bf16_rne(cw[((size_t)(a * 64 + co) * 64 + ci0 + 2 * jj + 1) * 9 + tap]);
        d[jj] = (unsigned)h0 | ((unsigned)h1 << 16);
    }
    *(i32x4*)(apack + ((((size_t)(a * 9 + tap) * 2 + ks) * 4 + mf) * 1024 + lane * 16)) =
        *(i32x4*)d;
}

// ---------------------------------------------------------------------------
// Layer 0: 1 -> 64 channels + ReLU, output bf16 [a][row][col][64].
// grid (y=256, a=4), 256 threads = x. Weights are block-uniform -> s_loads.
__global__ void conv_first_kernel(const float* __restrict__ img,
                                  const float* __restrict__ cw0,
                                  const float* __restrict__ cb0,
                                  unsigned short* __restrict__ act) {
    int y = blockIdx.x, a = blockIdx.y, x = threadIdx.x;
    float p[3][3];
    #pragma unroll
    for (int ty = 0; ty < 3; ++ty)
        #pragma unroll
        for (int tx = 0; tx < 3; ++tx) {
            int py = y + ty - 1, px = x + tx - 1;
            p[ty][tx] = ((unsigned)py < 256u && (unsigned)px < 256u)
                        ? img[py * 256 + px] : 0.0f;
        }
    const float* w = cw0 + (size_t)a * 64 * 9;
    const float* b = cb0 + a * 64;
    unsigned pk[32];
    #pragma unroll
    for (int co = 0; co < 64; ++co) {
        const float* wc = w + co * 9;
        float acc = b[co];
        #pragma unroll
        for (int ty = 0; ty < 3; ++ty)
            #pragma unroll
            for (int tx = 0; tx < 3; ++tx)
                acc = fmaf(wc[ty * 3 + tx], p[ty][tx], acc);
        acc = fmaxf(acc, 0.0f);
        unsigned short hv = cvt_bf16_rne(acc);
        if (co & 1) pk[co >> 1] |= ((unsigned)hv << 16);
        else        pk[co >> 1] = (unsigned)hv;
    }
    char* ob = (char*)act + (((size_t)(a << 16) + (y << 8) + x) << 7);
    #pragma unroll
    for (int k = 0; k < 8; ++k)
        *(i32x4*)(ob + k * 16) = *(i32x4*)&pk[k * 4];
}

// ---------------------------------------------------------------------------
// Mid layers 64->64 + ReLU via bf16 MFMA implicit GEMM.
// WG = 256 thr (4 waves), tile = 8 rows x 32 cols, all 64 co.
// LDS: 10x34 halo pixel tile, 144 B/pixel (8x16B ci-octets + 16B pad).
// grid dim3(8, 32, 4).
__global__ __launch_bounds__(256, 3)
void conv_mid_mfma(const unsigned short* __restrict__ act_in,
                   const char* __restrict__ apack_l,
                   const float* __restrict__ cb,
                   unsigned short* __restrict__ act_out) {
    __shared__ i32x4 lds4[340 * 9];
    int tid = threadIdx.x;
    int a = blockIdx.z;
    int r0 = blockIdx.y * 8, c0 = blockIdx.x * 32;
    const char* actb = (const char*)act_in;

    for (int s = tid; s < 2720; s += 256) {
        int px = s >> 3, o = s & 7;
        int prow = px / 34, pcol = px - prow * 34;
        int grow = r0 - 1 + prow, gcol = c0 - 1 + pcol;
        i32x4 v = {0, 0, 0, 0};
        if ((unsigned)grow < 256u && (unsigned)gcol < 256u)
            v = *(const i32x4*)(actb + (((size_t)(a << 16) + (grow << 8) + gcol) << 7) + (o << 4));
        lds4[px * 9 + o] = v;
    }
    __syncthreads();

    int lane = tid & 63, wv = tid >> 6;
    int n = lane & 15, q = lane >> 4;

    f32x4 acc[4][4];
    #pragma unroll
    for (int mf = 0; mf < 4; ++mf) {
        f32x4 bb = *(const f32x4*)(cb + a * 64 + mf * 16 + q * 4);
        #pragma unroll
        for (int nf = 0; nf < 4; ++nf) acc[mf][nf] = bb;
    }

    int base_nf[4];
    #pragma unroll
    for (int nf = 0; nf < 4; ++nf) {
        int orl = wv * 2 + (nf >> 1);
        int ocl = ((nf & 1) << 4) + n;
        base_nf[nf] = (orl * 34 + ocl) * 9 + q;  // i32x4 index at ty=tx=0,ks=0
    }
    const char* ap = apack_l + (size_t)a * 9 * 8192 + lane * 16;

    #pragma unroll
    for (int tap = 0; tap < 9; ++tap) {
        const int ty = tap / 3, tx = tap - ty * 3;
        const int toff = (ty * 34 + tx) * 9;
        #pragma unroll
        for (int ks = 0; ks < 2; ++ks) {
            bf16x8 Af[4], Bf[4];
            #pragma unroll
            for (int mf = 0; mf < 4; ++mf)
                Af[mf] = __builtin_bit_cast(bf16x8,
                    *(const i32x4*)(ap + (((tap * 2 + ks) * 4 + mf) << 10)));
            #pragma unroll
            for (int nf = 0; nf < 4; ++nf)
                Bf[nf] = __builtin_bit_cast(bf16x8, lds4[base_nf[nf] + toff + ks * 4]);
            #pragma unroll
            for (int mf = 0; mf < 4; ++mf)
                #pragma unroll
                for (int nf = 0; nf < 4; ++nf)
                    acc[mf][nf] = __builtin_amdgcn_mfma_f32_16x16x32_bf16(
                        Af[mf], Bf[nf], acc[mf][nf], 0, 0, 0);
        }
    }

    #pragma unroll
    for (int nf = 0; nf < 4; ++nf) {
        int grow = r0 + wv * 2 + (nf >> 1);
        int gcol = c0 + ((nf & 1) << 4) + n;
        char* ob = (char*)act_out + (((size_t)(a << 16) + (grow << 8) + gcol) << 7) + q * 8;
        #pragma unroll
        for (int mf = 0; mf < 4; ++mf) {
            f32x4 v = acc[mf][nf];
            unsigned d0 = (unsigned)cvt_bf16_rne(fmaxf(v.x, 0.0f))
                        | ((unsigned)cvt_bf16_rne(fmaxf(v.y, 0.0f)) << 16);
            unsigned d1 = (unsigned)cvt_bf16_rne(fmaxf(v.z, 0.0f))
                        | ((unsigned)cvt_bf16_rne(fmaxf(v.w, 0.0f)) << 16);
            uint2 st; st.x = d0; st.y = d1;
            *(uint2*)(ob + mf * 32) = st;
        }
    }
}

// ---------------------------------------------------------------------------
// Layer 4: 64 -> 1, no ReLU, fp32 out W_a[a][256][256].
// 8 lanes per pixel (lane&7 = ci octet) -> fully coalesced 1KB loads,
// width-8 shuffle reduce. grid (y=256, a=4), 256 threads.
__global__ void conv_last_kernel(const unsigned short* __restrict__ act,
                                 const float* __restrict__ cw4,
                                 const float* __restrict__ cb4,
                                 float* __restrict__ W_a) {
    int y = blockIdx.x, a = blockIdx.y;
    int tid = threadIdx.x;
    int lane = tid & 63, wv = tid >> 6;
    int o = lane & 7, pl = lane >> 3;
    float wr[8][9];
    #pragma unroll
    for (int j = 0; j < 8; ++j) {
        const float* wp = cw4 + ((size_t)a * 64 + o * 8 + j) * 9;
        #pragma unroll
        for (int t = 0; t < 9; ++t) wr[j][t] = wp[t];
    }
    const char* actb = (const char*)act;
    float bias = cb4[a];
    for (int i = 0; i < 8; ++i) {
        int x = i * 32 + wv * 8 + pl;
        float p = 0.0f;
        #pragma unroll
        for (int ty = 0; ty < 3; ++ty) {
            int py = y + ty - 1;
            #pragma unroll
            for (int tx = 0; tx < 3; ++tx) {
                int px = x + tx - 1;
                if ((unsigned)py < 256u && (unsigned)px < 256u) {
                    i32x4 v = *(const i32x4*)(actb +
                        (((size_t)(a << 16) + (py << 8) + px) << 7) + (o << 4));
                    const unsigned* dv = (const unsigned*)&v;
                    #pragma unroll
                    for (int j = 0; j < 8; ++j) {
                        unsigned d = dv[j >> 1];
                        unsigned short us = (j & 1) ? (unsigned short)(d >> 16)
                                                    : (unsigned short)(d & 0xffffu);
                        p = fmaf(bf16_to_f32(us), wr[j][ty * 3 + tx], p);
                    }
                }
            }
        }
        p += __shfl_xor(p, 1, 64);
        p += __shfl_xor(p, 2, 64);
        p += __shfl_xor(p, 4, 64);
        if (o == 0) W_a[(size_t)(a << 16) + (y << 8) + x] = p + bias;
    }
}

// ---------------------------------------------------------------------------
__global__ void wy_kernel(const float* __restrict__ yv,
                          const int* __restrict__ actions,
                          const float* __restrict__ W_a,
                          float* __restrict__ Wy) {
    int b = blockIdx.x, x = threadIdx.x;
    int a = actions[b];
    const float* Wp = W_a + (size_t)a * 65536;
    const float* yb = yv + b * 256;
    float acc = 0.0f;
    #pragma unroll 8
    for (int h = 0; h < 256; ++h)
        acc = fmaf(yb[h], Wp[(size_t)h * 256 + x], acc);
    Wy[b * 256 + x] = acc;
}

// ---------------------------------------------------------------------------
__global__ void logits_kernel(const float* __restrict__ xv,
                              const void* __restrict__ mask,
                              const int* __restrict__ flag,
                              const float* __restrict__ Wy,
                              float* __restrict__ out) {
    int tid = threadIdx.x, lane = tid & 63, wave = tid >> 6;
    int b = blockIdx.y;
    int fl = *flag;
    float4 wy4 = *(const float4*)(Wy + b * 256 + lane * 4);
    const float* xb = xv + (size_t)b * 4096 * 256;
    int l0 = blockIdx.x * 128 + wave * 32;
    for (int li = 0; li < 32; ++li) {
        int l = l0 + li;
        const float4 x4 = *(const float4*)(xb + (size_t)l * 256 + lane * 4);
        float p = x4.x * wy4.x + x4.y * wy4.y + x4.z * wy4.z + x4.w * wy4.w;
        #pragma unroll
        for (int off = 32; off > 0; off >>= 1)
            p += __shfl_xor(p, off, 64);
        if (lane == 0) {
            size_t mi = (size_t)b * 4096 + l;
            bool msk;
            if (fl & 2)      msk = ((const float*)mask)[mi] != 0.0f;
            else if (fl & 1) msk = ((const unsigned char*)mask)[mi] != 0;
            else             msk = ((const int*)mask)[mi] != 0;
            out[mi] = msk ? -__builtin_inff() : p;
        }
    }
}

// ---------------------------------------------------------------------------
__global__ void softmax_kernel(float* __restrict__ out) {
    int b = blockIdx.x, tid = threadIdx.x;
    int lane = tid & 63, wid = tid >> 6;
    float* row = out + (size_t)b * 4096;
    float v[4];
    float m = -__builtin_inff();
    #pragma unroll
    for (int i = 0; i < 4; ++i) { v[i] = row[tid + i * 1024]; m = fmaxf(m, v[i]); }
    #pragma unroll
    for (int off = 32; off > 0; off >>= 1) m = fmaxf(m, __shfl_xor(m, off, 64));
    __shared__ float redm[16];
    __shared__ float reds[16];
    if (lane == 0) redm[wid] = m;
    __syncthreads();
    float M = redm[0];
    #pragma unroll
    for (int j = 1; j < 16; ++j) M = fmaxf(M, redm[j]);
    float s = 0.0f;
    #pragma unroll
    for (int i = 0; i < 4; ++i) { v[i] = expf(v[i] - M); s += v[i]; }
    #pragma unroll
    for (int off = 32; off > 0; off >>= 1) s += __shfl_xor(s, off, 64);
    if (lane == 0) reds[wid] = s;
    __syncthreads();
    float S = 0.0f;
    #pragma unroll
    for (int j = 0; j < 16; ++j) S += reds[j];
    float inv = 1.0f / S;
    #pragma unroll
    for (int i = 0; i < 4; ++i) row[tid + i * 1024] = v[i] * inv;
}

// ---------------------------------------------------------------------------
extern "C" void kernel_launch(void* const* d_in, const int* in_sizes, int n_in,
                              void* d_out, int out_size, void* d_ws, size_t ws_size,
                              hipStream_t stream) {
    const float* xv      = (const float*)d_in[0];
    const float* yv      = (const float*)d_in[1];
    const void*  xmask   = d_in[2];
    const int*   actions = (const int*)d_in[3];
    const float* weight  = (const float*)d_in[4];
    const float* cw0 = (const float*)d_in[5];
    const float* cb0 = (const float*)d_in[6];
    const float* cw1 = (const float*)d_in[7];
    const float* cb1 = (const float*)d_in[8];
    const float* cw2 = (const float*)d_in[9];
    const float* cb2 = (const float*)d_in[10];
    const float* cw3 = (const float*)d_in[11];
    const float* cb3 = (const float*)d_in[12];
    const float* cw4 = (const float*)d_in[13];
    const float* cb4 = (const float*)d_in[14];
    float* out = (float*)d_out;

    char* ws = (char*)d_ws;
    unsigned short* bufA = (unsigned short*)ws;                    // 33554432 B
    unsigned short* bufB = (unsigned short*)(ws + 33554432);       // 33554432 B
    char*  apack = ws + 67108864;                                  // 3 x 294912 B
    float* W_a   = (float*)(ws + 67993600);                        // 1048576 B
    float* Wy    = (float*)(ws + 69042176);                        // 32768 B
    int*   flag  = (int*)(ws + 69074944);

    clear_flag_kernel<<<1, 64, 0, stream>>>(flag);
    detect_mask_kernel<<<32, 256, 0, stream>>>((const unsigned int*)xmask, flag);

    apack_kernel<<<dim3(9, 4), 512, 0, stream>>>(cw1, apack);
    apack_kernel<<<dim3(9, 4), 512, 0, stream>>>(cw2, apack + 294912);
    apack_kernel<<<dim3(9, 4), 512, 0, stream>>>(cw3, apack + 589824);

    conv_first_kernel<<<dim3(256, 4), 256, 0, stream>>>(weight, cw0, cb0, bufA);
    conv_mid_mfma<<<dim3(8, 32, 4), 256, 0, stream>>>(bufA, apack,          cb1, bufB);
    conv_mid_mfma<<<dim3(8, 32, 4), 256, 0, stream>>>(bufB, apack + 294912, cb2, bufA);
    conv_mid_mfma<<<dim3(8, 32, 4), 256, 0, stream>>>(bufA, apack + 589824, cb3, bufB);
    conv_last_kernel<<<dim3(256, 4), 256, 0, stream>>>(bufB, cw4, cb4, W_a);

    wy_kernel<<<32, 256, 0, stream>>>(yv, actions, W_a, Wy);
    logits_kernel<<<dim3(32, 32), 256, 0, stream>>>(xv, xmask, flag, Wy, out);
    softmax_kernel<<<32, 1024, 0, stream>>>(out);
}